// Round 12
// baseline (109.496 us; speedup 1.0000x reference)
//
#include <hip/hip_runtime.h>
#include <hip/hip_bf16.h>

typedef short bf16x8 __attribute__((ext_vector_type(8)));
typedef float f32x4 __attribute__((ext_vector_type(4)));
typedef float f32x16 __attribute__((ext_vector_type(16)));
typedef long l64x2 __attribute__((ext_vector_type(2)));
typedef unsigned short u16;
typedef unsigned char u8;

#define NB2 (-0.35f * 1.44269504088896340736f)
#define P2C (0.70f * 1.44269504088896340736f)
#define MF8(a,b,c)  __builtin_amdgcn_mfma_f32_32x32x16_fp8_fp8(a, b, c, 0, 0, 0)
#define MFB(a,b,c)  __builtin_amdgcn_mfma_f32_32x32x16_bf16(a, b, c, 0, 0, 0)

__device__ __forceinline__ u16 f2bf(float f) {
  union { float f; unsigned int u; } v; v.f = f;
  unsigned int x = v.u;
  return (u16)((x + 0x7FFFu + ((x >> 16) & 1u)) >> 16);
}

__device__ __forceinline__ unsigned cvtpk(float lo, float hi) {
  unsigned r;
  asm("v_cvt_pk_bf16_f32 %0, %1, %2" : "=v"(r) : "v"(lo), "v"(hi));
  return r;
}

__device__ __forceinline__ void pswap(unsigned &a, unsigned &b) {
  asm volatile("v_permlane32_swap_b32 %0, %1" : "+v"(a), "+v"(b));
}

__device__ __forceinline__ u8 f2e4m3(float f) {
  unsigned int u = __float_as_uint(f);
  u8 s = (u8)((u >> 24) & 0x80u);
  float a = fabsf(f);
  if (a >= 448.f) return s | 0x7E;
  if (a < 0.015625f) return s | (u8)(int)rintf(a * 512.f);
  unsigned int m = u & 0x7fffffffu;
  unsigned int r = m + 0x7FFFFu + ((m >> 20) & 1u);
  return s | (u8)((((r >> 23) - 120u) << 3) | ((r >> 20) & 7u));
}

__device__ __forceinline__ unsigned int pk4(float a, float b, float c, float d) {
#if __has_builtin(__builtin_amdgcn_cvt_pk_fp8_f32)
  int v = __builtin_amdgcn_cvt_pk_fp8_f32(a, b, 0, false);
  v = __builtin_amdgcn_cvt_pk_fp8_f32(c, d, v, true);
  return (unsigned int)v;
#else
  return (unsigned int)f2e4m3(a) | ((unsigned int)f2e4m3(b) << 8)
       | ((unsigned int)f2e4m3(c) << 16) | ((unsigned int)f2e4m3(d) << 24);
#endif
}

#define GLOAD_LDS(g, l) __builtin_amdgcn_global_load_lds( \
    (const __attribute__((address_space(1))) unsigned int*)(g), \
    (__attribute__((address_space(3))) unsigned int*)(l), 16, 0, 0)

// ---------- prep: x -> fp8 frag-stream [rowtile(512)][p(16)][lane(64)]16B + xsq ----------
__global__ __launch_bounds__(512)
void prep_x8(const float* __restrict__ src, u8* __restrict__ dst,
             float* __restrict__ sq) {
  const int row = blockIdx.x * 8 + (threadIdx.x >> 6);
  const int i6 = threadIdx.x & 63;
  const float4* p = (const float4*)(src + (size_t)row * 512) + i6 * 2;
  float4 a = p[0], b = p[1];
  float ss = a.x*a.x + a.y*a.y + a.z*a.z + a.w*a.w
           + b.x*b.x + b.y*b.y + b.z*b.z + b.w*b.w;
  uint2 o;
  o.x = pk4(a.x, a.y, a.z, a.w);
  o.y = pk4(b.x, b.y, b.z, b.w);
  const int pp = i6 >> 2, sub = (i6 >> 1) & 1, h = i6 & 1;
  const int l = (h << 5) | (row & 31);
  *(uint2*)(dst + (size_t)(row >> 5) * 16384 + pp * 1024 + l * 16 + sub * 8) = o;
  ss += __shfl_xor(ss, 1);  ss += __shfl_xor(ss, 2);
  ss += __shfl_xor(ss, 4);  ss += __shfl_xor(ss, 8);
  ss += __shfl_xor(ss, 16); ss += __shfl_xor(ss, 32);
  if (i6 == 0) sq[row] = ss;
}

// ---------- prep: centers -> fp8 frag-stream [chunk(128)][p(16)][cgrp(4)][swz unit(16)]16B + csq ----------
__global__ __launch_bounds__(256)
void prep_cen(const float* __restrict__ cen, u8* __restrict__ cfr,
              float* __restrict__ csq) {
  const int t = threadIdx.x;
  const int c = blockIdx.x * 4 + (t >> 6);
  const int i6 = t & 63;
  const float* p = cen + (size_t)c * 512 + i6 * 8;
  float4 a = *(const float4*)p, b = *(const float4*)(p + 4);
  float ss = a.x*a.x + a.y*a.y + a.z*a.z + a.w*a.w
           + b.x*b.x + b.y*b.y + b.z*b.z + b.w*b.w;
  uint2 o;
  o.x = pk4(a.x, a.y, a.z, a.w);
  o.y = pk4(b.x, b.y, b.z, b.w);
  const int pp = i6 >> 2, sub = (i6 >> 1) & 1, h = i6 & 1;
  const int lc = c & 31;
  const int v = (((lc & 7) * 2 + h) ^ ((lc >> 2) & 1));
  *(uint2*)(cfr + (size_t)(c >> 5) * 16384 + pp * 1024 + (lc >> 3) * 256
            + v * 16 + sub * 8) = o;
  ss += __shfl_xor(ss, 1);  ss += __shfl_xor(ss, 2);
  ss += __shfl_xor(ss, 4);  ss += __shfl_xor(ss, 8);
  ss += __shfl_xor(ss, 16); ss += __shfl_xor(ss, 32);
  if (i6 == 0) csq[c] = ss;
}

// ---------- prep: W [4096][128] f32 -> per-lane-contig bf16 units ----------
// element (o,c): byte = (c>>5)*8192 + (o>>5)*2048 + (((c&31)>>4))*1024
//                     + ((((c&15)>>3)*32) + (o&31))*16 + (c&7)*2
__global__ __launch_bounds__(256)
void prep_w(const float* __restrict__ W, u8* __restrict__ wt) {
  __shared__ u16 t_[128 * 66];
  const int c0 = blockIdx.x * 64;
  const int t = threadIdx.x;
#pragma unroll
  for (int it = 0; it < 32; ++it) {
    int idx = it * 256 + t;
    int cl = idx >> 7;
    int o  = idx & 127;
    t_[o * 66 + cl] = f2bf(W[(size_t)(c0 + cl) * 128 + o]);
  }
  __syncthreads();
#pragma unroll
  for (int it = 0; it < 4; ++it) {
    int idx = it * 256 + t;            // 0..1023 : 16B units
    int o  = idx >> 3;
    int uu = idx & 7;
    int ch = uu >> 2;                  // local chunk 0/1
    int kt = (uu >> 1) & 1;
    int h  = uu & 1;
    u16* d = (u16*)(wt + ((size_t)(c0 >> 5) + ch) * 8192 + (o >> 5) * 2048
                    + kt * 1024 + (h * 32 + (o & 31)) * 16);
    const u16* s_ = &t_[o * 66 + ch * 32 + kt * 16 + h * 8];
#pragma unroll
    for (int j = 0; j < 8; ++j) d[j] = s_[j];
  }
}

// ---------- init: out = bias ----------
__global__ __launch_bounds__(256)
void init_out(const float* __restrict__ bias, float* __restrict__ out) {
  const int i4 = blockIdx.x * 256 + threadIdx.x;
  float4 b = ((const float4*)bias)[i4 & 31];
  ((float4*)out)[i4] = b;
}

// ---------- main: 512 blocks(256thr) = 128 row-tiles(128r) x 4 quarters ----------
// W via L2->regs; cs 3-buffer with counted vmcnt (never drains mid-loop).
__global__ __launch_bounds__(256, 2)
void rbf_main(const u8* __restrict__ xfs, const u8* __restrict__ cfr,
              const u8* __restrict__ wtgb, const float* __restrict__ csq_g,
              const float* __restrict__ xsq_g, float* __restrict__ out)
{
  __shared__ __align__(16) u8 cs[3][16384];   // center chunk 3-buf (32c x 512k fp8 stream)
  __shared__ __align__(16) float csq_l[1024];
  __shared__ __align__(16) float xsq_l[128];

  const int tid = threadIdx.x;
  const int lane = tid & 63;
  const int wv = tid >> 6;                 // wave 0..3 -> rows wv*32..+32
  const int l31 = lane & 31;
  const int h = lane >> 5;
  const int bid = blockIdx.x;
  const int chq = bid & 3;
  const size_t r0 = (size_t)(bid >> 2) * 128;

#define S_CS(cc) do { \
    const u8* sG_ = cfr + ((size_t)(chq * 32 + (cc)) << 14) + tid * 16; \
    u8* sL_ = &cs[(cc) % 3][0] + tid * 16; \
    GLOAD_LDS(sG_,         sL_); \
    GLOAD_LDS(sG_ + 4096,  sL_ + 4096); \
    GLOAD_LDS(sG_ + 8192,  sL_ + 8192); \
    GLOAD_LDS(sG_ + 12288, sL_ + 12288); \
  } while (0)

  // prologue staging
  if (tid < 32) GLOAD_LDS(xsq_g + r0 + tid * 4, xsq_l + tid * 4);
  GLOAD_LDS(csq_g + chq * 1024 + tid * 4, csq_l + tid * 4);
  S_CS(0);
  S_CS(1);

  // x fragments: 16 x b128 coalesced from frag-stream
  l64x2 xf[16];
  {
    const u8* xb = xfs + ((size_t)((bid >> 2) * 4 + wv)) * 16384 + lane * 16;
#pragma unroll
    for (int p = 0; p < 16; ++p)
      xf[p] = *(const l64x2*)(xb + p * 1024);
  }

  asm volatile("s_waitcnt vmcnt(0)" ::: "memory");
  __builtin_amdgcn_s_barrier();
  __builtin_amdgcn_sched_barrier(0);

  const float xn = NB2 * xsq_l[wv * 32 + l31];

  // GEMM1 A-operand LDS base (octet-distinct bank quads)
  const int cbase = ((l31 >> 3) & 3) * 256
                  + ((((l31 & 7) * 2 + h) ^ ((l31 >> 2) & 1)) << 4);

  const f32x16 z16 = {0,0,0,0,0,0,0,0,0,0,0,0,0,0,0,0};
  f32x16 oa0 = z16, oa1 = z16, oa2 = z16, oa3 = z16;

#pragma unroll 1
  for (int cc = 0; cc < 32; ++cc) {
    // ---- W chunk -> regs (issue FIRST; consumed at TAIL ~2500cy later) ----
    const u8* wgb = wtgb + ((size_t)(chq * 32 + cc) << 13) + lane * 16;
    bf16x8 w00 = *(const bf16x8*)(wgb);
    bf16x8 w01 = *(const bf16x8*)(wgb + 1024);
    bf16x8 w10 = *(const bf16x8*)(wgb + 2048);
    bf16x8 w11 = *(const bf16x8*)(wgb + 3072);
    bf16x8 w20 = *(const bf16x8*)(wgb + 4096);
    bf16x8 w21 = *(const bf16x8*)(wgb + 5120);
    bf16x8 w30 = *(const bf16x8*)(wgb + 6144);
    bf16x8 w31 = *(const bf16x8*)(wgb + 7168);
    __builtin_amdgcn_sched_barrier(0);
    if (cc < 30) S_CS(cc + 2);
    __builtin_amdgcn_sched_barrier(0);

    const u8* csb = &cs[cc % 3][0];

    // ---- GEMM1 (swapped): D[c][m]; A=centers(LDS), B=x(regs); split-K 2 chains ----
    f32x16 s0 = z16, s1 = z16;
#pragma unroll
    for (int p = 0; p < 16; ++p) {
      l64x2 A = *(const l64x2*)(csb + p * 1024 + cbase);
      __builtin_amdgcn_s_setprio(1);
      if (p & 1) {
        s1 = MF8(A[0], xf[p][0], s1);
        s1 = MF8(A[1], xf[p][1], s1);
      } else {
        s0 = MF8(A[0], xf[p][0], s0);
        s0 = MF8(A[1], xf[p][1], s0);
      }
      __builtin_amdgcn_s_setprio(0);
    }

    // ---- rbf in registers: lane m=l31; reg r -> c = (r&3) + 8*(r>>2) + 4*h ----
    f32x4 cq0 = *(const f32x4*)(csq_l + cc * 32 + 0  + 4 * h);
    f32x4 cq1 = *(const f32x4*)(csq_l + cc * 32 + 8  + 4 * h);
    f32x4 cq2 = *(const f32x4*)(csq_l + cc * 32 + 16 + 4 * h);
    f32x4 cq3 = *(const f32x4*)(csq_l + cc * 32 + 24 + 4 * h);
    float e[16];
#pragma unroll
    for (int r = 0; r < 16; ++r) {
      const float cq = (r < 4 ? cq0[r] : r < 8 ? cq1[r - 4] : r < 12 ? cq2[r - 8] : cq3[r - 12]);
      e[r] = __builtin_amdgcn_exp2f(fmaf(s0[r] + s1[r], P2C, fmaf(cq, NB2, xn)));
    }
    unsigned P0 = cvtpk(e[0],  e[1]),  P1 = cvtpk(e[2],  e[3]);
    unsigned P2 = cvtpk(e[4],  e[5]),  P3 = cvtpk(e[6],  e[7]);
    unsigned P4 = cvtpk(e[8],  e[9]),  P5 = cvtpk(e[10], e[11]);
    unsigned P6 = cvtpk(e[12], e[13]), P7 = cvtpk(e[14], e[15]);
    pswap(P0, P2); pswap(P1, P3);      // F: c 0..15
    pswap(P4, P6); pswap(P5, P7);      // G: c 16..31
    union { unsigned u[4]; bf16x8 v; } FA, GA;
    FA.u[0] = P0; FA.u[1] = P1; FA.u[2] = P2; FA.u[3] = P3;
    GA.u[0] = P4; GA.u[1] = P5; GA.u[2] = P6; GA.u[3] = P7;

    // ---- TAIL: wait W regs (counted: cs(cc+2) stays in flight), GEMM2 from regs ----
    if (cc < 30) { asm volatile("s_waitcnt vmcnt(4)" ::: "memory"); }
    else         { asm volatile("s_waitcnt vmcnt(0)" ::: "memory"); }
    __builtin_amdgcn_sched_barrier(0);
    __builtin_amdgcn_s_setprio(1);
    oa0 = MFB(FA.v, w00, oa0);
    oa0 = MFB(GA.v, w01, oa0);
    oa1 = MFB(FA.v, w10, oa1);
    oa1 = MFB(GA.v, w11, oa1);
    oa2 = MFB(FA.v, w20, oa2);
    oa2 = MFB(GA.v, w21, oa2);
    oa3 = MFB(FA.v, w30, oa3);
    oa3 = MFB(GA.v, w31, oa3);
    __builtin_amdgcn_s_setprio(0);

    __builtin_amdgcn_s_barrier();           // slot-reuse guard only; no drain
    __builtin_amdgcn_sched_barrier(0);
  }

  // epilogue: out += partial; D rows m=(r&3)+8*(r>>2)+4h, cols o=ot*32+l31
#pragma unroll
  for (int r = 0; r < 16; ++r) {
    const int m = wv * 32 + (r & 3) + 8 * (r >> 2) + 4 * h;
    float* op = &out[(r0 + m) * 128 + l31];
    atomicAdd(op,      oa0[r]);
    atomicAdd(op + 32, oa1[r]);
    atomicAdd(op + 64, oa2[r]);
    atomicAdd(op + 96, oa3[r]);
  }
#undef S_CS
}

extern "C" void kernel_launch(void* const* d_in, const int* in_sizes, int n_in,
                              void* d_out, int out_size, void* d_ws, size_t ws_size,
                              hipStream_t stream) {
  (void)in_sizes; (void)n_in; (void)out_size; (void)ws_size;
  const float* x   = (const float*)d_in[0];
  const float* cen = (const float*)d_in[1];
  const float* W   = (const float*)d_in[2];
  const float* b   = (const float*)d_in[3];
  u8* xfs = (u8*)d_ws;                          // 8 MB (x frag-stream)
  u8* cfr = xfs + (size_t)16384 * 512;          // 2 MB (center frag-stream)
  u8* wtgb = cfr + (size_t)4096 * 512;          // 1 MB (W per-lane-contig units)
  float* csq = (float*)(wtgb + (size_t)128 * 4096 * 2);  // 16 KB
  float* xsq = csq + 4096;                      // 64 KB
  prep_x8<<<2048, 512, 0, stream>>>(x, xfs, xsq);
  prep_cen<<<1024, 256, 0, stream>>>(cen, cfr, csq);
  prep_w<<<64, 256, 0, stream>>>(W, wtgb);
  init_out<<<2048, 256, 0, stream>>>(b, (float*)d_out);
  rbf_main<<<512, 256, 0, stream>>>(xfs, cfr, wtgb, csq, xsq, (float*)d_out);
}

// Round 13
// 106.246 us; speedup vs baseline: 1.0306x; 1.0306x over previous
//
#include <hip/hip_runtime.h>
#include <hip/hip_bf16.h>

typedef short bf16x8 __attribute__((ext_vector_type(8)));
typedef float f32x4 __attribute__((ext_vector_type(4)));
typedef float f32x16 __attribute__((ext_vector_type(16)));
typedef long l64x2 __attribute__((ext_vector_type(2)));
typedef unsigned short u16;
typedef unsigned char u8;

#define NB2 (-0.35f * 1.44269504088896340736f)
#define P2C (0.70f * 1.44269504088896340736f)
#define MF8(a,b,c)  __builtin_amdgcn_mfma_f32_32x32x16_fp8_fp8(a, b, c, 0, 0, 0)
#define MFB(a,b,c)  __builtin_amdgcn_mfma_f32_32x32x16_bf16(a, b, c, 0, 0, 0)

__device__ __forceinline__ u16 f2bf(float f) {
  union { float f; unsigned int u; } v; v.f = f;
  unsigned int x = v.u;
  return (u16)((x + 0x7FFFu + ((x >> 16) & 1u)) >> 16);
}

__device__ __forceinline__ unsigned cvtpk(float lo, float hi) {
  unsigned r;
  asm("v_cvt_pk_bf16_f32 %0, %1, %2" : "=v"(r) : "v"(lo), "v"(hi));
  return r;
}

__device__ __forceinline__ void pswap(unsigned &a, unsigned &b) {
  asm volatile("v_permlane32_swap_b32 %0, %1" : "+v"(a), "+v"(b));
}

__device__ __forceinline__ u8 f2e4m3(float f) {
  unsigned int u = __float_as_uint(f);
  u8 s = (u8)((u >> 24) & 0x80u);
  float a = fabsf(f);
  if (a >= 448.f) return s | 0x7E;
  if (a < 0.015625f) return s | (u8)(int)rintf(a * 512.f);
  unsigned int m = u & 0x7fffffffu;
  unsigned int r = m + 0x7FFFFu + ((m >> 20) & 1u);
  return s | (u8)((((r >> 23) - 120u) << 3) | ((r >> 20) & 7u));
}

__device__ __forceinline__ unsigned int pk4(float a, float b, float c, float d) {
#if __has_builtin(__builtin_amdgcn_cvt_pk_fp8_f32)
  int v = __builtin_amdgcn_cvt_pk_fp8_f32(a, b, 0, false);
  v = __builtin_amdgcn_cvt_pk_fp8_f32(c, d, v, true);
  return (unsigned int)v;
#else
  return (unsigned int)f2e4m3(a) | ((unsigned int)f2e4m3(b) << 8)
       | ((unsigned int)f2e4m3(c) << 16) | ((unsigned int)f2e4m3(d) << 24);
#endif
}

#define GLOAD_LDS(g, l) __builtin_amdgcn_global_load_lds( \
    (const __attribute__((address_space(1))) unsigned int*)(g), \
    (__attribute__((address_space(3))) unsigned int*)(l), 16, 0, 0)

// ---------- prep: x -> fp8 frag-stream [rowtile(512)][p(16)][lane(64)]16B + xsq ----------
__global__ __launch_bounds__(512)
void prep_x8(const float* __restrict__ src, u8* __restrict__ dst,
             float* __restrict__ sq) {
  const int row = blockIdx.x * 8 + (threadIdx.x >> 6);
  const int i6 = threadIdx.x & 63;
  const float4* p = (const float4*)(src + (size_t)row * 512) + i6 * 2;
  float4 a = p[0], b = p[1];
  float ss = a.x*a.x + a.y*a.y + a.z*a.z + a.w*a.w
           + b.x*b.x + b.y*b.y + b.z*b.z + b.w*b.w;
  uint2 o;
  o.x = pk4(a.x, a.y, a.z, a.w);
  o.y = pk4(b.x, b.y, b.z, b.w);
  const int pp = i6 >> 2, sub = (i6 >> 1) & 1, h = i6 & 1;
  const int l = (h << 5) | (row & 31);
  *(uint2*)(dst + (size_t)(row >> 5) * 16384 + pp * 1024 + l * 16 + sub * 8) = o;
  ss += __shfl_xor(ss, 1);  ss += __shfl_xor(ss, 2);
  ss += __shfl_xor(ss, 4);  ss += __shfl_xor(ss, 8);
  ss += __shfl_xor(ss, 16); ss += __shfl_xor(ss, 32);
  if (i6 == 0) sq[row] = ss;
}

// ---------- prep: centers -> fp8 frag-stream [chunk(128)][p(16)][cgrp(4)][swz unit(16)]16B + csq ----------
__global__ __launch_bounds__(256)
void prep_cen(const float* __restrict__ cen, u8* __restrict__ cfr,
              float* __restrict__ csq) {
  const int t = threadIdx.x;
  const int c = blockIdx.x * 4 + (t >> 6);
  const int i6 = t & 63;
  const float* p = cen + (size_t)c * 512 + i6 * 8;
  float4 a = *(const float4*)p, b = *(const float4*)(p + 4);
  float ss = a.x*a.x + a.y*a.y + a.z*a.z + a.w*a.w
           + b.x*b.x + b.y*b.y + b.z*b.z + b.w*b.w;
  uint2 o;
  o.x = pk4(a.x, a.y, a.z, a.w);
  o.y = pk4(b.x, b.y, b.z, b.w);
  const int pp = i6 >> 2, sub = (i6 >> 1) & 1, h = i6 & 1;
  const int lc = c & 31;
  const int v = (((lc & 7) * 2 + h) ^ ((lc >> 2) & 1));
  *(uint2*)(cfr + (size_t)(c >> 5) * 16384 + pp * 1024 + (lc >> 3) * 256
            + v * 16 + sub * 8) = o;
  ss += __shfl_xor(ss, 1);  ss += __shfl_xor(ss, 2);
  ss += __shfl_xor(ss, 4);  ss += __shfl_xor(ss, 8);
  ss += __shfl_xor(ss, 16); ss += __shfl_xor(ss, 32);
  if (i6 == 0) csq[c] = ss;
}

// ---------- prep: W [4096][128] f32 -> per-lane-contig bf16 units ----------
__global__ __launch_bounds__(256)
void prep_w(const float* __restrict__ W, u8* __restrict__ wt) {
  __shared__ u16 t_[128 * 66];
  const int c0 = blockIdx.x * 64;
  const int t = threadIdx.x;
#pragma unroll
  for (int it = 0; it < 32; ++it) {
    int idx = it * 256 + t;
    int cl = idx >> 7;
    int o  = idx & 127;
    t_[o * 66 + cl] = f2bf(W[(size_t)(c0 + cl) * 128 + o]);
  }
  __syncthreads();
#pragma unroll
  for (int it = 0; it < 4; ++it) {
    int idx = it * 256 + t;            // 0..1023 : 16B units
    int o  = idx >> 3;
    int uu = idx & 7;
    int ch = uu >> 2;
    int kt = (uu >> 1) & 1;
    int h  = uu & 1;
    u16* d = (u16*)(wt + ((size_t)(c0 >> 5) + ch) * 8192 + (o >> 5) * 2048
                    + kt * 1024 + (h * 32 + (o & 31)) * 16);
    const u16* s_ = &t_[o * 66 + ch * 32 + kt * 16 + h * 8];
#pragma unroll
    for (int j = 0; j < 8; ++j) d[j] = s_[j];
  }
}

// ---------- init: out = bias ----------
__global__ __launch_bounds__(256)
void init_out(const float* __restrict__ bias, float* __restrict__ out) {
  const int i4 = blockIdx.x * 256 + threadIdx.x;
  float4 b = ((const float4*)bias)[i4 & 31];
  ((float4*)out)[i4] = b;
}

// ---------- main: 512 blocks(256thr) = 128 row-tiles(128r) x 4 quarters ----------
// Rotated 2-stage pipeline: body cc = {W(cc)->regs, CS(cc+2), GEMM1(cc+1) || exp(cc), GEMM2(cc)}.
__global__ __launch_bounds__(256, 2)
void rbf_main(const u8* __restrict__ xfs, const u8* __restrict__ cfr,
              const u8* __restrict__ wtgb, const float* __restrict__ csq_g,
              const float* __restrict__ xsq_g, float* __restrict__ out)
{
  __shared__ __align__(16) u8 cs[4][16384];   // center chunk 4-buf
  __shared__ __align__(16) float csq_l[1024];
  __shared__ __align__(16) float xsq_l[128];

  const int tid = threadIdx.x;
  const int lane = tid & 63;
  const int wv = tid >> 6;
  const int l31 = lane & 31;
  const int h = lane >> 5;
  const int bid = blockIdx.x;
  const int chq = bid & 3;
  const size_t r0 = (size_t)(bid >> 2) * 128;

#define S_CS(cc) do { \
    const u8* sG_ = cfr + ((size_t)(chq * 32 + (cc)) << 14) + tid * 16; \
    u8* sL_ = &cs[(cc) & 3][0] + tid * 16; \
    GLOAD_LDS(sG_,         sL_); \
    GLOAD_LDS(sG_ + 4096,  sL_ + 4096); \
    GLOAD_LDS(sG_ + 8192,  sL_ + 8192); \
    GLOAD_LDS(sG_ + 12288, sL_ + 12288); \
  } while (0)

  // prologue staging
  if (tid < 32) GLOAD_LDS(xsq_g + r0 + tid * 4, xsq_l + tid * 4);
  GLOAD_LDS(csq_g + chq * 1024 + tid * 4, csq_l + tid * 4);
  S_CS(0);
  S_CS(1);

  // x fragments
  l64x2 xf[16];
  {
    const u8* xb = xfs + ((size_t)((bid >> 2) * 4 + wv)) * 16384 + lane * 16;
#pragma unroll
    for (int p = 0; p < 16; ++p)
      xf[p] = *(const l64x2*)(xb + p * 1024);
  }

  asm volatile("s_waitcnt vmcnt(0)" ::: "memory");
  __builtin_amdgcn_s_barrier();
  __builtin_amdgcn_sched_barrier(0);

  const float xn = NB2 * xsq_l[wv * 32 + l31];
  const int cbase = ((l31 >> 3) & 3) * 256
                  + ((((l31 & 7) * 2 + h) ^ ((l31 >> 2) & 1)) << 4);

  const f32x16 z16 = {0,0,0,0,0,0,0,0,0,0,0,0,0,0,0,0};
  f32x16 oa0 = z16, oa1 = z16, oa2 = z16, oa3 = z16;
  f32x16 sA0 = z16, sA1 = z16, sB0 = z16, sB1 = z16;

// GEMM1 quarter: p = 4Q..4Q+3 of chunk in CSB -> chains Na (even p), Nb (odd p)
#define G1Q(Na, Nb, Q, CSB, INIT) do { \
    l64x2 A0 = *(const l64x2*)((CSB) + (4*(Q)+0)*1024 + cbase); \
    l64x2 A1 = *(const l64x2*)((CSB) + (4*(Q)+1)*1024 + cbase); \
    l64x2 A2 = *(const l64x2*)((CSB) + (4*(Q)+2)*1024 + cbase); \
    l64x2 A3 = *(const l64x2*)((CSB) + (4*(Q)+3)*1024 + cbase); \
    __builtin_amdgcn_s_setprio(1); \
    if (INIT) { Na = MF8(A0[0], xf[4*(Q)+0][0], z16); \
                Nb = MF8(A1[0], xf[4*(Q)+1][0], z16); } \
    else      { Na = MF8(A0[0], xf[4*(Q)+0][0], Na); \
                Nb = MF8(A1[0], xf[4*(Q)+1][0], Nb); } \
    Na = MF8(A0[1], xf[4*(Q)+0][1], Na); \
    Nb = MF8(A1[1], xf[4*(Q)+1][1], Nb); \
    Na = MF8(A2[0], xf[4*(Q)+2][0], Na); \
    Nb = MF8(A3[0], xf[4*(Q)+3][0], Nb); \
    Na = MF8(A2[1], xf[4*(Q)+2][1], Na); \
    Nb = MF8(A3[1], xf[4*(Q)+3][1], Nb); \
    __builtin_amdgcn_s_setprio(0); \
  } while (0)

// exp quarter Q of chunk CC from chains Ca/Cb -> packed Pa,Pb
#define EXPQ(Ca, Cb, Q, CC, Pa, Pb) do { \
    f32x4 cqv = *(const f32x4*)(csq_l + (CC) * 32 + (Q) * 8 + 4 * h); \
    float e0_ = __builtin_amdgcn_exp2f(fmaf((Ca)[4*(Q)+0] + (Cb)[4*(Q)+0], P2C, fmaf(cqv[0], NB2, xn))); \
    float e1_ = __builtin_amdgcn_exp2f(fmaf((Ca)[4*(Q)+1] + (Cb)[4*(Q)+1], P2C, fmaf(cqv[1], NB2, xn))); \
    float e2_ = __builtin_amdgcn_exp2f(fmaf((Ca)[4*(Q)+2] + (Cb)[4*(Q)+2], P2C, fmaf(cqv[2], NB2, xn))); \
    float e3_ = __builtin_amdgcn_exp2f(fmaf((Ca)[4*(Q)+3] + (Cb)[4*(Q)+3], P2C, fmaf(cqv[3], NB2, xn))); \
    Pa = cvtpk(e0_, e1_); \
    Pb = cvtpk(e2_, e3_); \
  } while (0)

// body: consume chunk CC (chains Ca/Cb), build chunk CC+1 (chains Na/Nb)
#define BODY(CC, Ca, Cb, Na, Nb, VM) do { \
    asm volatile("s_waitcnt vmcnt(0)" ::: "memory"); \
    __builtin_amdgcn_s_barrier(); \
    __builtin_amdgcn_sched_barrier(0); \
    const u8* wgb = wtgb + ((size_t)(chq * 32 + (CC)) << 13) + lane * 16; \
    bf16x8 w00 = *(const bf16x8*)(wgb); \
    bf16x8 w01 = *(const bf16x8*)(wgb + 1024); \
    bf16x8 w10 = *(const bf16x8*)(wgb + 2048); \
    bf16x8 w11 = *(const bf16x8*)(wgb + 3072); \
    bf16x8 w20 = *(const bf16x8*)(wgb + 4096); \
    bf16x8 w21 = *(const bf16x8*)(wgb + 5120); \
    bf16x8 w30 = *(const bf16x8*)(wgb + 6144); \
    bf16x8 w31 = *(const bf16x8*)(wgb + 7168); \
    if ((CC) + 2 < 32) S_CS((CC) + 2); \
    __builtin_amdgcn_sched_barrier(0); \
    const u8* csb = &cs[((CC) + 1) & 3][0]; \
    unsigned P0, P1, P2, P3, P4, P5, P6, P7; \
    if ((CC) < 31) G1Q(Na, Nb, 0, csb, 1); \
    EXPQ(Ca, Cb, 0, CC, P0, P1); \
    if ((CC) < 31) G1Q(Na, Nb, 1, csb, 0); \
    EXPQ(Ca, Cb, 1, CC, P2, P3); \
    if ((CC) < 31) G1Q(Na, Nb, 2, csb, 0); \
    EXPQ(Ca, Cb, 2, CC, P4, P5); \
    if ((CC) < 31) G1Q(Na, Nb, 3, csb, 0); \
    EXPQ(Ca, Cb, 3, CC, P6, P7); \
    pswap(P0, P2); pswap(P1, P3); \
    pswap(P4, P6); pswap(P5, P7); \
    union { unsigned u[4]; bf16x8 v; } FA, GA; \
    FA.u[0] = P0; FA.u[1] = P1; FA.u[2] = P2; FA.u[3] = P3; \
    GA.u[0] = P4; GA.u[1] = P5; GA.u[2] = P6; GA.u[3] = P7; \
    asm volatile("s_waitcnt vmcnt(" #VM ")" ::: "memory"); \
    __builtin_amdgcn_sched_barrier(0); \
    __builtin_amdgcn_s_setprio(1); \
    oa0 = MFB(FA.v, w00, oa0); \
    oa1 = MFB(FA.v, w10, oa1); \
    oa2 = MFB(FA.v, w20, oa2); \
    oa3 = MFB(FA.v, w30, oa3); \
    oa0 = MFB(GA.v, w01, oa0); \
    oa1 = MFB(GA.v, w11, oa1); \
    oa2 = MFB(GA.v, w21, oa2); \
    oa3 = MFB(GA.v, w31, oa3); \
    __builtin_amdgcn_s_setprio(0); \
  } while (0)

  // prologue: GEMM1(0) -> sA (slot 0 already staged & drained)
  {
    const u8* csb0 = &cs[0][0];
    G1Q(sA0, sA1, 0, csb0, 1);
    G1Q(sA0, sA1, 1, csb0, 0);
    G1Q(sA0, sA1, 2, csb0, 0);
    G1Q(sA0, sA1, 3, csb0, 0);
  }

#pragma unroll 1
  for (int cc = 0; cc < 30; cc += 2) {
    BODY(cc,     sA0, sA1, sB0, sB1, 4);
    BODY(cc + 1, sB0, sB1, sA0, sA1, 4);
  }
  BODY(30, sA0, sA1, sB0, sB1, 0);
  BODY(31, sB0, sB1, sA0, sA1, 0);

  // epilogue: out += partial; D rows m=(r&3)+8*(r>>2)+4h, cols o=ot*32+l31
#pragma unroll
  for (int r = 0; r < 16; ++r) {
    const int m = wv * 32 + (r & 3) + 8 * (r >> 2) + 4 * h;
    float* op = &out[(r0 + m) * 128 + l31];
    atomicAdd(op,      oa0[r]);
    atomicAdd(op + 32, oa1[r]);
    atomicAdd(op + 64, oa2[r]);
    atomicAdd(op + 96, oa3[r]);
  }
#undef S_CS
#undef G1Q
#undef EXPQ
#undef BODY
}

extern "C" void kernel_launch(void* const* d_in, const int* in_sizes, int n_in,
                              void* d_out, int out_size, void* d_ws, size_t ws_size,
                              hipStream_t stream) {
  (void)in_sizes; (void)n_in; (void)out_size; (void)ws_size;
  const float* x   = (const float*)d_in[0];
  const float* cen = (const float*)d_in[1];
  const float* W   = (const float*)d_in[2];
  const float* b   = (const float*)d_in[3];
  u8* xfs = (u8*)d_ws;                          // 8 MB (x frag-stream)
  u8* cfr = xfs + (size_t)16384 * 512;          // 2 MB (center frag-stream)
  u8* wtgb = cfr + (size_t)4096 * 512;          // 1 MB (W per-lane-contig units)
  float* csq = (float*)(wtgb + (size_t)128 * 4096 * 2);  // 16 KB
  float* xsq = csq + 4096;                      // 64 KB
  prep_x8<<<2048, 512, 0, stream>>>(x, xfs, xsq);
  prep_cen<<<1024, 256, 0, stream>>>(cen, cfr, csq);
  prep_w<<<64, 256, 0, stream>>>(W, wtgb);
  init_out<<<2048, 256, 0, stream>>>(b, (float*)d_out);
  rbf_main<<<512, 256, 0, stream>>>(xfs, cfr, wtgb, csq, xsq, (float*)d_out);
}